// Round 1
// baseline (1387.608 us; speedup 1.0000x reference)
//
#include <hip/hip_runtime.h>

#define HD 64  // hidden == out dim

// ---------------- CSR build ----------------

__global__ void k_deg(const int* __restrict__ dst, int* __restrict__ deg, int E) {
  int e = blockIdx.x * blockDim.x + threadIdx.x;
  if (e < E) atomicAdd(&deg[dst[e]], 1);
}

__global__ void k_dinv(const int* __restrict__ deg, float* __restrict__ dinv, int N) {
  int i = blockIdx.x * blockDim.x + threadIdx.x;
  if (i < N) dinv[i] = rsqrtf((float)deg[i] + 1.0f);
}

// chunk = 1024 elements per block (256 threads x 4)
__global__ void k_scan1(const int* __restrict__ deg, int* __restrict__ row_start,
                        int* __restrict__ partials, int N) {
  __shared__ int sh[256];
  int t = threadIdx.x;
  int base = blockIdx.x * 1024 + t * 4;
  int v0 = 0, v1 = 0, v2 = 0, v3 = 0;
  if (base + 0 < N) v0 = deg[base + 0];
  if (base + 1 < N) v1 = deg[base + 1];
  if (base + 2 < N) v2 = deg[base + 2];
  if (base + 3 < N) v3 = deg[base + 3];
  int tsum = v0 + v1 + v2 + v3;
  sh[t] = tsum;
  __syncthreads();
  for (int off = 1; off < 256; off <<= 1) {
    int x = (t >= off) ? sh[t - off] : 0;
    __syncthreads();
    sh[t] += x;
    __syncthreads();
  }
  int excl = sh[t] - tsum;
  if (t == 255) partials[blockIdx.x] = sh[255];
  if (base + 0 < N) row_start[base + 0] = excl;
  if (base + 1 < N) row_start[base + 1] = excl + v0;
  if (base + 2 < N) row_start[base + 2] = excl + v0 + v1;
  if (base + 3 < N) row_start[base + 3] = excl + v0 + v1 + v2;
}

__global__ void k_scan2(int* partials, int nb) {  // nb <= 256
  __shared__ int sh[256];
  int t = threadIdx.x;
  int v = (t < nb) ? partials[t] : 0;
  sh[t] = v;
  __syncthreads();
  for (int off = 1; off < 256; off <<= 1) {
    int x = (t >= off) ? sh[t - off] : 0;
    __syncthreads();
    sh[t] += x;
    __syncthreads();
  }
  if (t < nb) partials[t] = sh[t] - v;  // exclusive
}

__global__ void k_scan3(int* __restrict__ row_start, const int* __restrict__ partials,
                        int N, int E) {
  int i = blockIdx.x * blockDim.x + threadIdx.x;
  if (i < N) row_start[i] += partials[i >> 10];
  if (i == 0) row_start[N] = E;
}

__global__ void k_fill(const int* __restrict__ src, const int* __restrict__ dst,
                       const int* __restrict__ row_start, int* __restrict__ cursor,
                       int* __restrict__ edge_src, int E) {
  int e = blockIdx.x * blockDim.x + threadIdx.x;
  if (e < E) {
    int d = dst[e];
    int pos = atomicAdd(&cursor[d], 1);
    edge_src[row_start[d] + pos] = src[e];
  }
}

// ---------------- GEMM: H[N x 64] = X[N x K] @ W[K x 64] ----------------
// one wave handles ROWS rows; lane = output column.
template <int K, int ROWS>
__global__ void k_gemm(const float* __restrict__ X, const float* __restrict__ W,
                       float* __restrict__ H, int N) {
  int lane = threadIdx.x & 63;
  int wid = (blockIdx.x * blockDim.x + threadIdx.x) >> 6;
  int row0 = wid * ROWS;
  if (row0 >= N) return;
  if (row0 + ROWS <= N) {
    float acc[ROWS];
#pragma unroll
    for (int r = 0; r < ROWS; r++) acc[r] = 0.f;
    int urow = __builtin_amdgcn_readfirstlane(row0);
    const float* x0 = X + (size_t)urow * K;
#pragma unroll 4
    for (int k = 0; k < K; k++) {
      float wv = W[k * HD + lane];
#pragma unroll
      for (int r = 0; r < ROWS; r++) acc[r] = fmaf(x0[(size_t)r * K + k], wv, acc[r]);
    }
#pragma unroll
    for (int r = 0; r < ROWS; r++) H[(size_t)(row0 + r) * HD + lane] = acc[r];
  } else {
    for (int r = 0; r < ROWS; r++) {
      int row = row0 + r;
      if (row >= N) break;
      float a = 0.f;
      for (int k = 0; k < K; k++) a = fmaf(X[(size_t)row * K + k], W[k * HD + lane], a);
      H[(size_t)row * HD + lane] = a;
    }
  }
}

// ---------------- Aggregation: out = scatter-norm-sum + self + bias (+relu) ----
// one wave per node, lane = channel
__global__ void k_agg(const float* __restrict__ H, const int* __restrict__ edge_src,
                      const int* __restrict__ row_start, const float* __restrict__ dinv,
                      const float* __restrict__ bias, float* __restrict__ out, int N,
                      int relu) {
  int lane = threadIdx.x & 63;
  int node = (blockIdx.x * blockDim.x + threadIdx.x) >> 6;
  if (node >= N) return;
  float di = dinv[node];
  float acc = H[(size_t)node * HD + lane] * (di * di);
  int beg = row_start[node], end = row_start[node + 1];
  for (int e = beg; e < end; ++e) {
    int s = edge_src[e];
    acc = fmaf(H[(size_t)s * HD + lane], dinv[s] * di, acc);
  }
  acc += bias[lane];
  if (relu) acc = fmaxf(acc, 0.f);
  out[(size_t)node * HD + lane] = acc;
}

// ---------------- zscore ----------------

__global__ void k_colstats(const float* __restrict__ H, float* __restrict__ stats, int N) {
  __shared__ float ss[256], sq[256];
  int t = threadIdx.x;
  int col = t & 63, grp = t >> 6;
  float s = 0.f, q = 0.f;
  for (int row = blockIdx.x * 4 + grp; row < N; row += gridDim.x * 4) {
    float v = H[(size_t)row * HD + col];
    s += v;
    q += v * v;
  }
  ss[t] = s;
  sq[t] = q;
  __syncthreads();
  if (t < 64) {
    s = ss[t] + ss[t + 64] + ss[t + 128] + ss[t + 192];
    q = sq[t] + sq[t + 64] + sq[t + 128] + sq[t + 192];
    atomicAdd(&stats[t], s);
    atomicAdd(&stats[64 + t], q);
  }
}

__global__ void k_normalize(float* __restrict__ H, const float* __restrict__ stats, int N) {
  int i = blockIdx.x * blockDim.x + threadIdx.x;
  int total = N * HD;
  if (i >= total) return;
  int col = i & 63;
  float sum = stats[col], sumsq = stats[64 + col];
  float mean = sum / (float)N;
  float var = (sumsq - sum * sum / (float)N) / (float)(N - 1);
  float r = rsqrtf(var);
  H[i] = (H[i] - mean) * r;
}

// ---------------- launch ----------------

extern "C" void kernel_launch(void* const* d_in, const int* in_sizes, int n_in,
                              void* d_out, int out_size, void* d_ws, size_t ws_size,
                              hipStream_t stream) {
  const int IN_DIM = 256;
  const float* X[2] = {(const float*)d_in[0], (const float*)d_in[2]};
  const int* EI[2] = {(const int*)d_in[1], (const int*)d_in[3]};
  const float* W1 = (const float*)d_in[4];
  const float* b1 = (const float*)d_in[5];
  const float* W2 = (const float*)d_in[6];
  const float* b2 = (const float*)d_in[7];
  const int N = in_sizes[0] / IN_DIM;
  const int E = in_sizes[1] / 2;

  // workspace carve-up (~59 MB)
  char* ws = (char*)d_ws;
  size_t off = 0;
  auto carve = [&](size_t bytes) -> char* {
    char* p = ws + off;
    off += (bytes + 255) & ~(size_t)255;
    return p;
  };
  float* bufA = (float*)carve((size_t)N * HD * 4);
  float* bufB = (float*)carve((size_t)N * HD * 4);
  int* edge_src = (int*)carve((size_t)E * 4);
  // contiguous zero region: deg[N] | cursor[N] | stats[128]
  char* zero_base = carve(((size_t)2 * N + 128) * 4);
  int* deg = (int*)zero_base;
  int* cursor = deg + N;
  float* stats = (float*)(cursor + N);
  int* row_start = (int*)carve((size_t)(N + 1) * 4);
  float* dinv = (float*)carve((size_t)N * 4);
  int* partials = (int*)carve(256 * 4);
  (void)ws_size; (void)n_in; (void)out_size;

  const int T = 256;
  const int gE = (E + T - 1) / T;
  const int gN = (N + T - 1) / T;
  const int nchunk = (N + 1023) / 1024;
  const int gWave4 = (N + 3) / 4;          // one wave per node, 4 waves/block
  const int gGemm = ((N + 3) / 4 + 3) / 4; // 4 rows/wave, 4 waves/block
  const int gElem = (N * HD + T - 1) / T;

  for (int g = 0; g < 2; ++g) {
    const float* x = X[g];
    const int* src = EI[g];
    const int* dst = EI[g] + E;
    float* OUT = (float*)d_out + (size_t)g * N * HD;

    hipMemsetAsync(zero_base, 0, ((size_t)2 * N + 128) * 4, stream);
    k_deg<<<gE, T, 0, stream>>>(dst, deg, E);
    k_dinv<<<gN, T, 0, stream>>>(deg, dinv, N);
    k_scan1<<<nchunk, T, 0, stream>>>(deg, row_start, partials, N);
    k_scan2<<<1, T, 0, stream>>>(partials, nchunk);
    k_scan3<<<gN, T, 0, stream>>>(row_start, partials, N, E);
    k_fill<<<gE, T, 0, stream>>>(src, dst, row_start, cursor, edge_src, E);

    // layer 1: h = relu(agg(x @ W1) + b1)
    k_gemm<256, 4><<<gGemm, T, 0, stream>>>(x, W1, bufA, N);
    k_agg<<<gWave4, T, 0, stream>>>(bufA, edge_src, row_start, dinv, b1, bufB, N, 1);
    // layer 2: h = agg(h1 @ W2) + b2  -> straight into d_out segment
    k_gemm<64, 4><<<gGemm, T, 0, stream>>>(bufB, W2, bufA, N);
    k_agg<<<gWave4, T, 0, stream>>>(bufA, edge_src, row_start, dinv, b2, OUT, N, 0);

    // zscore in place on OUT
    k_colstats<<<512, T, 0, stream>>>(OUT, stats, N);
    k_normalize<<<gElem, T, 0, stream>>>(OUT, stats, N);
  }
}

// Round 2
// 924.716 us; speedup vs baseline: 1.5006x; 1.5006x over previous
//
#include <hip/hip_runtime.h>

#define HD 64  // hidden == out dim

typedef __attribute__((ext_vector_type(8))) short bf16x8;
typedef __attribute__((ext_vector_type(4))) float f32x4;
typedef __attribute__((ext_vector_type(4))) unsigned short u16x4;

__device__ inline unsigned short f2bf(float x) {
  unsigned u = __float_as_uint(x);
  unsigned r = u + 0x7FFF + ((u >> 16) & 1);
  return (unsigned short)(r >> 16);
}
__device__ inline float bf2f(unsigned short h) {
  return __uint_as_float(((unsigned)h) << 16);
}

// ---------------- CSR build ----------------

__global__ void k_deg(const int* __restrict__ dst, int* __restrict__ deg, int E) {
  int e = blockIdx.x * blockDim.x + threadIdx.x;
  if (e < E) atomicAdd(&deg[dst[e]], 1);
}

__global__ void k_dinv(const int* __restrict__ deg, float* __restrict__ dinv, int N) {
  int i = blockIdx.x * blockDim.x + threadIdx.x;
  if (i < N) dinv[i] = rsqrtf((float)deg[i] + 1.0f);
}

// chunk = 1024 elements per block (256 threads x 4)
__global__ void k_scan1(const int* __restrict__ deg, int* __restrict__ row_start,
                        int* __restrict__ partials, int N) {
  __shared__ int sh[256];
  int t = threadIdx.x;
  int base = blockIdx.x * 1024 + t * 4;
  int v0 = 0, v1 = 0, v2 = 0, v3 = 0;
  if (base + 0 < N) v0 = deg[base + 0];
  if (base + 1 < N) v1 = deg[base + 1];
  if (base + 2 < N) v2 = deg[base + 2];
  if (base + 3 < N) v3 = deg[base + 3];
  int tsum = v0 + v1 + v2 + v3;
  sh[t] = tsum;
  __syncthreads();
  for (int off = 1; off < 256; off <<= 1) {
    int x = (t >= off) ? sh[t - off] : 0;
    __syncthreads();
    sh[t] += x;
    __syncthreads();
  }
  int excl = sh[t] - tsum;
  if (t == 255) partials[blockIdx.x] = sh[255];
  if (base + 0 < N) row_start[base + 0] = excl;
  if (base + 1 < N) row_start[base + 1] = excl + v0;
  if (base + 2 < N) row_start[base + 2] = excl + v0 + v1;
  if (base + 3 < N) row_start[base + 3] = excl + v0 + v1 + v2;
}

__global__ void k_scan2(int* partials, int nb) {  // nb <= 256
  __shared__ int sh[256];
  int t = threadIdx.x;
  int v = (t < nb) ? partials[t] : 0;
  sh[t] = v;
  __syncthreads();
  for (int off = 1; off < 256; off <<= 1) {
    int x = (t >= off) ? sh[t - off] : 0;
    __syncthreads();
    sh[t] += x;
    __syncthreads();
  }
  if (t < nb) partials[t] = sh[t] - v;  // exclusive
}

__global__ void k_scan3(int* __restrict__ row_start, const int* __restrict__ partials,
                        int N, int E) {
  int i = blockIdx.x * blockDim.x + threadIdx.x;
  if (i < N) row_start[i] += partials[i >> 10];
  if (i == 0) row_start[N] = E;
}

__global__ void k_fill(const int* __restrict__ src, const int* __restrict__ dst,
                       const int* __restrict__ row_start, int* __restrict__ cursor,
                       const float* __restrict__ dinv, int* __restrict__ edge_src,
                       float* __restrict__ edge_norm, int E) {
  int e = blockIdx.x * blockDim.x + threadIdx.x;
  if (e < E) {
    int d = dst[e], s = src[e];
    int pos = atomicAdd(&cursor[d], 1);
    int slot = row_start[d] + pos;
    edge_src[slot] = s;
    edge_norm[slot] = dinv[s] * dinv[d];
  }
}

// ---------------- GEMM via bf16-split MFMA ----------------
// H[N x 64] = X[N x K] @ W[K x 64], fp32 in/out, internally bf16 hi/lo split
// (3 MFMA passes: hi*hi + hi*lo + lo*hi -> ~2^-16 relative error).
// Block: 256 threads = 4 waves; tile 64 rows x 64 cols; K chunked by KC.
template <int K, int KC>
__global__ __launch_bounds__(256) void k_gemm_mfma(const float* __restrict__ X,
                                                   const float* __restrict__ W,
                                                   float* __restrict__ H, int N) {
  constexpr int KP = KC + 8;  // padded row length (bf16 elems); keeps 16B align + breaks banks
  __shared__ unsigned short sAhi[64 * KP];
  __shared__ unsigned short sAlo[64 * KP];
  __shared__ unsigned short sBhi[64 * KP];  // [col][k] transposed
  __shared__ unsigned short sBlo[64 * KP];

  const int tid = threadIdx.x;
  const int row0 = blockIdx.x * 64;
  const int lane = tid & 63;
  const int wv = tid >> 6;
  const int r16 = lane & 15;
  const int half = lane >> 4;

  f32x4 acc[4];
#pragma unroll
  for (int f = 0; f < 4; ++f) acc[f] = (f32x4){0.f, 0.f, 0.f, 0.f};

  for (int ch = 0; ch < K / KC; ++ch) {
    const int kc0 = ch * KC;
    // ---- stage A tile: 64 rows x KC, float4 loads -> hi/lo bf16 ----
    constexpr int KCV = KC / 4;
    for (int idx = tid; idx < 64 * KCV; idx += 256) {
      int r = idx / KCV, c4 = idx % KCV;
      int grow = row0 + r;
      float4 v;
      if (grow < N)
        v = *(const float4*)&X[(size_t)grow * K + kc0 + c4 * 4];
      else
        v = make_float4(0.f, 0.f, 0.f, 0.f);
      u16x4 hi, lo;
      float vv[4] = {v.x, v.y, v.z, v.w};
#pragma unroll
      for (int j = 0; j < 4; ++j) {
        unsigned short h = f2bf(vv[j]);
        hi[j] = h;
        lo[j] = f2bf(vv[j] - bf2f(h));
      }
      *(u16x4*)&sAhi[r * KP + c4 * 4] = hi;
      *(u16x4*)&sAlo[r * KP + c4 * 4] = lo;
    }
    // ---- stage B tile transposed: W[kc0+k][c] -> sB[c][k] ----
    for (int idx = tid; idx < KC * 64; idx += 256) {
      int k = idx >> 6, c = idx & 63;
      float wval = W[(size_t)(kc0 + k) * HD + c];
      unsigned short h = f2bf(wval);
      sBhi[c * KP + k] = h;
      sBlo[c * KP + k] = f2bf(wval - bf2f(h));
    }
    __syncthreads();
    // ---- MFMA over this chunk ----
#pragma unroll
    for (int ks = 0; ks < KC; ks += 32) {
      const int ka = ks + half * 8;
      bf16x8 ahi = *(const bf16x8*)&sAhi[(wv * 16 + r16) * KP + ka];
      bf16x8 alo = *(const bf16x8*)&sAlo[(wv * 16 + r16) * KP + ka];
#pragma unroll
      for (int f = 0; f < 4; ++f) {
        bf16x8 bhi = *(const bf16x8*)&sBhi[(f * 16 + r16) * KP + ka];
        bf16x8 blo = *(const bf16x8*)&sBlo[(f * 16 + r16) * KP + ka];
        acc[f] = __builtin_amdgcn_mfma_f32_16x16x32_bf16(ahi, bhi, acc[f], 0, 0, 0);
        acc[f] = __builtin_amdgcn_mfma_f32_16x16x32_bf16(ahi, blo, acc[f], 0, 0, 0);
        acc[f] = __builtin_amdgcn_mfma_f32_16x16x32_bf16(alo, bhi, acc[f], 0, 0, 0);
      }
    }
    __syncthreads();
  }
  // ---- store: C layout col=lane&15, row=(lane>>4)*4+reg ----
  const int orow0 = row0 + wv * 16 + half * 4;
#pragma unroll
  for (int f = 0; f < 4; ++f) {
#pragma unroll
    for (int rg = 0; rg < 4; ++rg) {
      int orow = orow0 + rg;
      if (orow < N) H[(size_t)orow * HD + f * 16 + r16] = acc[f][rg];
    }
  }
}

// ---------------- Aggregation: gather + norm-sum + self + bias (+relu) ----
// one wave per node, lane = channel; 4-deep unrolled gathers
__global__ void k_agg(const float* __restrict__ H, const int* __restrict__ edge_src,
                      const float* __restrict__ edge_norm,
                      const int* __restrict__ row_start, const float* __restrict__ dinv,
                      const float* __restrict__ bias, float* __restrict__ out, int N,
                      int relu) {
  int lane = threadIdx.x & 63;
  int node = (blockIdx.x * blockDim.x + threadIdx.x) >> 6;
  if (node >= N) return;
  float di = dinv[node];
  float acc = H[(size_t)node * HD + lane] * (di * di);
  int beg = row_start[node], end = row_start[node + 1];
  int e = beg;
  for (; e + 4 <= end; e += 4) {
    int s0 = edge_src[e + 0], s1 = edge_src[e + 1];
    int s2 = edge_src[e + 2], s3 = edge_src[e + 3];
    float n0 = edge_norm[e + 0], n1 = edge_norm[e + 1];
    float n2 = edge_norm[e + 2], n3 = edge_norm[e + 3];
    float h0 = H[(size_t)s0 * HD + lane];
    float h1 = H[(size_t)s1 * HD + lane];
    float h2 = H[(size_t)s2 * HD + lane];
    float h3 = H[(size_t)s3 * HD + lane];
    acc = fmaf(h0, n0, acc);
    acc = fmaf(h1, n1, acc);
    acc = fmaf(h2, n2, acc);
    acc = fmaf(h3, n3, acc);
  }
  for (; e < end; ++e) acc = fmaf(H[(size_t)edge_src[e] * HD + lane], edge_norm[e], acc);
  acc += bias[lane];
  if (relu) acc = fmaxf(acc, 0.f);
  out[(size_t)node * HD + lane] = acc;
}

// ---------------- zscore ----------------

__global__ void k_colstats(const float* __restrict__ H, float* __restrict__ stats, int N) {
  __shared__ float ss[256], sq[256];
  int t = threadIdx.x;
  int col = t & 63, grp = t >> 6;
  float s = 0.f, q = 0.f;
  for (int row = blockIdx.x * 4 + grp; row < N; row += gridDim.x * 4) {
    float v = H[(size_t)row * HD + col];
    s += v;
    q += v * v;
  }
  ss[t] = s;
  sq[t] = q;
  __syncthreads();
  if (t < 64) {
    s = ss[t] + ss[t + 64] + ss[t + 128] + ss[t + 192];
    q = sq[t] + sq[t + 64] + sq[t + 128] + sq[t + 192];
    atomicAdd(&stats[t], s);
    atomicAdd(&stats[64 + t], q);
  }
}

__global__ void k_normalize(float* __restrict__ H, const float* __restrict__ stats, int N) {
  int i = blockIdx.x * blockDim.x + threadIdx.x;
  int total = N * HD;
  if (i >= total) return;
  int col = i & 63;
  float sum = stats[col], sumsq = stats[64 + col];
  float mean = sum / (float)N;
  float var = (sumsq - sum * sum / (float)N) / (float)(N - 1);
  float r = rsqrtf(var);
  H[i] = (H[i] - mean) * r;
}

// ---------------- launch ----------------

extern "C" void kernel_launch(void* const* d_in, const int* in_sizes, int n_in,
                              void* d_out, int out_size, void* d_ws, size_t ws_size,
                              hipStream_t stream) {
  const int IN_DIM = 256;
  const float* X[2] = {(const float*)d_in[0], (const float*)d_in[2]};
  const int* EI[2] = {(const int*)d_in[1], (const int*)d_in[3]};
  const float* W1 = (const float*)d_in[4];
  const float* b1 = (const float*)d_in[5];
  const float* W2 = (const float*)d_in[6];
  const float* b2 = (const float*)d_in[7];
  const int N = in_sizes[0] / IN_DIM;
  const int E = in_sizes[1] / 2;

  // workspace carve-up (~66 MB)
  char* ws = (char*)d_ws;
  size_t off = 0;
  auto carve = [&](size_t bytes) -> char* {
    char* p = ws + off;
    off += (bytes + 255) & ~(size_t)255;
    return p;
  };
  float* bufA = (float*)carve((size_t)N * HD * 4);
  float* bufB = (float*)carve((size_t)N * HD * 4);
  int* edge_src = (int*)carve((size_t)E * 4);
  float* edge_norm = (float*)carve((size_t)E * 4);
  // contiguous zero region: deg[N] | cursor[N] | stats[128]
  char* zero_base = carve(((size_t)2 * N + 128) * 4);
  int* deg = (int*)zero_base;
  int* cursor = deg + N;
  float* stats = (float*)(cursor + N);
  int* row_start = (int*)carve((size_t)(N + 1) * 4);
  float* dinv = (float*)carve((size_t)N * 4);
  int* partials = (int*)carve(256 * 4);
  (void)ws_size; (void)n_in; (void)out_size;

  const int T = 256;
  const int gE = (E + T - 1) / T;
  const int gN = (N + T - 1) / T;
  const int nchunk = (N + 1023) / 1024;
  const int gWave4 = (N + 3) / 4;    // one wave per node, 4 waves/block
  const int gGemm = (N + 63) / 64;   // 64 rows per block
  const int gElem = (N * HD + T - 1) / T;

  for (int g = 0; g < 2; ++g) {
    const float* x = X[g];
    const int* src = EI[g];
    const int* dst = EI[g] + E;
    float* OUT = (float*)d_out + (size_t)g * N * HD;

    hipMemsetAsync(zero_base, 0, ((size_t)2 * N + 128) * 4, stream);
    k_deg<<<gE, T, 0, stream>>>(dst, deg, E);
    k_dinv<<<gN, T, 0, stream>>>(deg, dinv, N);
    k_scan1<<<nchunk, T, 0, stream>>>(deg, row_start, partials, N);
    k_scan2<<<1, T, 0, stream>>>(partials, nchunk);
    k_scan3<<<gN, T, 0, stream>>>(row_start, partials, N, E);
    k_fill<<<gE, T, 0, stream>>>(src, dst, row_start, cursor, dinv, edge_src, edge_norm, E);

    // layer 1: h = relu(agg(x @ W1) + b1)
    k_gemm_mfma<256, 128><<<gGemm, T, 0, stream>>>(x, W1, bufA, N);
    k_agg<<<gWave4, T, 0, stream>>>(bufA, edge_src, edge_norm, row_start, dinv, b1, bufB, N, 1);
    // layer 2: h = agg(h1 @ W2) + b2  -> straight into d_out segment
    k_gemm_mfma<64, 64><<<gGemm, T, 0, stream>>>(bufB, W2, bufA, N);
    k_agg<<<gWave4, T, 0, stream>>>(bufA, edge_src, edge_norm, row_start, dinv, b2, OUT, N, 0);

    // zscore in place on OUT
    k_colstats<<<512, T, 0, stream>>>(OUT, stats, N);
    k_normalize<<<gElem, T, 0, stream>>>(OUT, stats, N);
  }
}

// Round 3
// 837.835 us; speedup vs baseline: 1.6562x; 1.1037x over previous
//
#include <hip/hip_runtime.h>

#define HD 64  // hidden == out dim

typedef __attribute__((ext_vector_type(8))) short bf16x8;
typedef __attribute__((ext_vector_type(4))) float f32x4;
typedef __attribute__((ext_vector_type(4))) unsigned short u16x4;

__device__ inline unsigned short f2bf(float x) {
  unsigned u = __float_as_uint(x);
  unsigned r = u + 0x7FFF + ((u >> 16) & 1);
  return (unsigned short)(r >> 16);
}
__device__ inline float bf2f(unsigned short h) {
  return __uint_as_float(((unsigned)h) << 16);
}

// ---------------- CSR build ----------------

__global__ void k_deg(const int* __restrict__ dst, int* __restrict__ deg, int E) {
  int e = blockIdx.x * blockDim.x + threadIdx.x;
  if (e < E) atomicAdd(&deg[dst[e]], 1);
}

// chunk = 1024 elements per block (256 threads x 4); also emits dinv = rsqrt(deg+1)
__global__ void k_scan1(const int* __restrict__ deg, int* __restrict__ row_start,
                        int* __restrict__ partials, float* __restrict__ dinv, int N) {
  __shared__ int sh[256];
  int t = threadIdx.x;
  int base = blockIdx.x * 1024 + t * 4;
  int v0 = 0, v1 = 0, v2 = 0, v3 = 0;
  if (base + 0 < N) v0 = deg[base + 0];
  if (base + 1 < N) v1 = deg[base + 1];
  if (base + 2 < N) v2 = deg[base + 2];
  if (base + 3 < N) v3 = deg[base + 3];
  if (base + 0 < N) dinv[base + 0] = rsqrtf((float)v0 + 1.0f);
  if (base + 1 < N) dinv[base + 1] = rsqrtf((float)v1 + 1.0f);
  if (base + 2 < N) dinv[base + 2] = rsqrtf((float)v2 + 1.0f);
  if (base + 3 < N) dinv[base + 3] = rsqrtf((float)v3 + 1.0f);
  int tsum = v0 + v1 + v2 + v3;
  sh[t] = tsum;
  __syncthreads();
  for (int off = 1; off < 256; off <<= 1) {
    int x = (t >= off) ? sh[t - off] : 0;
    __syncthreads();
    sh[t] += x;
    __syncthreads();
  }
  int excl = sh[t] - tsum;
  if (t == 255) partials[blockIdx.x] = sh[255];
  if (base + 0 < N) row_start[base + 0] = excl;
  if (base + 1 < N) row_start[base + 1] = excl + v0;
  if (base + 2 < N) row_start[base + 2] = excl + v0 + v1;
  if (base + 3 < N) row_start[base + 3] = excl + v0 + v1 + v2;
}

__global__ void k_scan2(int* partials, int nb) {  // nb <= 256
  __shared__ int sh[256];
  int t = threadIdx.x;
  int v = (t < nb) ? partials[t] : 0;
  sh[t] = v;
  __syncthreads();
  for (int off = 1; off < 256; off <<= 1) {
    int x = (t >= off) ? sh[t - off] : 0;
    __syncthreads();
    sh[t] += x;
    __syncthreads();
  }
  if (t < nb) partials[t] = sh[t] - v;  // exclusive
}

__global__ void k_scan3(int* __restrict__ row_start, const int* __restrict__ partials,
                        int N, int E) {
  int i = blockIdx.x * blockDim.x + threadIdx.x;
  if (i < N) row_start[i] += partials[i >> 10];
  if (i == 0) row_start[N] = E;
}

// one packed 8B record per edge: {src, norm}
__global__ void k_fill(const int* __restrict__ src, const int* __restrict__ dst,
                       const int* __restrict__ row_start, int* __restrict__ cursor,
                       const float* __restrict__ dinv, int2* __restrict__ recs, int E) {
  int e = blockIdx.x * blockDim.x + threadIdx.x;
  if (e < E) {
    int d = dst[e], s = src[e];
    int pos = atomicAdd(&cursor[d], 1);
    int2 rec;
    rec.x = s;
    rec.y = __float_as_int(dinv[s] * dinv[d]);
    recs[row_start[d] + pos] = rec;
  }
}

// ---------------- GEMM via bf16-split MFMA ----------------
// Hb[N x 64] (bf16) = X[N x K] @ W[K x 64], fp32 in, bf16 out.
// internally bf16 hi/lo split (3 MFMA passes -> ~2^-16 relative error before
// the final bf16 output rounding).
template <int K, int KC>
__global__ __launch_bounds__(256) void k_gemm_mfma(const float* __restrict__ X,
                                                   const float* __restrict__ W,
                                                   unsigned short* __restrict__ Hb, int N) {
  constexpr int KP = KC + 8;  // padded row (bf16 elems): 16B-aligned rows + bank break
  __shared__ unsigned short sAhi[64 * KP];
  __shared__ unsigned short sAlo[64 * KP];
  __shared__ unsigned short sBhi[64 * KP];  // [col][k] transposed
  __shared__ unsigned short sBlo[64 * KP];

  const int tid = threadIdx.x;
  const int row0 = blockIdx.x * 64;
  const int lane = tid & 63;
  const int wv = tid >> 6;
  const int r16 = lane & 15;
  const int half = lane >> 4;

  f32x4 acc[4];
#pragma unroll
  for (int f = 0; f < 4; ++f) acc[f] = (f32x4){0.f, 0.f, 0.f, 0.f};

  for (int ch = 0; ch < K / KC; ++ch) {
    const int kc0 = ch * KC;
    constexpr int KCV = KC / 4;
    for (int idx = tid; idx < 64 * KCV; idx += 256) {
      int r = idx / KCV, c4 = idx % KCV;
      int grow = row0 + r;
      float4 v;
      if (grow < N)
        v = *(const float4*)&X[(size_t)grow * K + kc0 + c4 * 4];
      else
        v = make_float4(0.f, 0.f, 0.f, 0.f);
      u16x4 hi, lo;
      float vv[4] = {v.x, v.y, v.z, v.w};
#pragma unroll
      for (int j = 0; j < 4; ++j) {
        unsigned short h = f2bf(vv[j]);
        hi[j] = h;
        lo[j] = f2bf(vv[j] - bf2f(h));
      }
      *(u16x4*)&sAhi[r * KP + c4 * 4] = hi;
      *(u16x4*)&sAlo[r * KP + c4 * 4] = lo;
    }
    for (int idx = tid; idx < KC * 64; idx += 256) {
      int k = idx >> 6, c = idx & 63;
      float wval = W[(size_t)(kc0 + k) * HD + c];
      unsigned short h = f2bf(wval);
      sBhi[c * KP + k] = h;
      sBlo[c * KP + k] = f2bf(wval - bf2f(h));
    }
    __syncthreads();
#pragma unroll
    for (int ks = 0; ks < KC; ks += 32) {
      const int ka = ks + half * 8;
      bf16x8 ahi = *(const bf16x8*)&sAhi[(wv * 16 + r16) * KP + ka];
      bf16x8 alo = *(const bf16x8*)&sAlo[(wv * 16 + r16) * KP + ka];
#pragma unroll
      for (int f = 0; f < 4; ++f) {
        bf16x8 bhi = *(const bf16x8*)&sBhi[(f * 16 + r16) * KP + ka];
        bf16x8 blo = *(const bf16x8*)&sBlo[(f * 16 + r16) * KP + ka];
        acc[f] = __builtin_amdgcn_mfma_f32_16x16x32_bf16(ahi, bhi, acc[f], 0, 0, 0);
        acc[f] = __builtin_amdgcn_mfma_f32_16x16x32_bf16(ahi, blo, acc[f], 0, 0, 0);
        acc[f] = __builtin_amdgcn_mfma_f32_16x16x32_bf16(alo, bhi, acc[f], 0, 0, 0);
      }
    }
    __syncthreads();
  }
  // store bf16: C layout col=lane&15, row=(lane>>4)*4+reg
  const int orow0 = row0 + wv * 16 + half * 4;
#pragma unroll
  for (int f = 0; f < 4; ++f) {
#pragma unroll
    for (int rg = 0; rg < 4; ++rg) {
      int orow = orow0 + rg;
      if (orow < N) Hb[(size_t)orow * HD + f * 16 + r16] = f2bf(acc[f][rg]);
    }
  }
}

// ---------------- Aggregation: bf16 gathers + f32 accumulate ----------------
// one wave per node, lane = channel; 4-deep unrolled gathers
__global__ void k_agg(const unsigned short* __restrict__ Hb, const int2* __restrict__ recs,
                      const int* __restrict__ row_start, const float* __restrict__ dinv,
                      const float* __restrict__ bias, float* __restrict__ out, int N,
                      int relu) {
  int lane = threadIdx.x & 63;
  int node = (blockIdx.x * blockDim.x + threadIdx.x) >> 6;
  if (node >= N) return;
  float di = dinv[node];
  float acc = bf2f(Hb[(size_t)node * HD + lane]) * (di * di);
  int beg = row_start[node], end = row_start[node + 1];
  int e = beg;
  for (; e + 4 <= end; e += 4) {
    int2 r0 = recs[e + 0], r1 = recs[e + 1], r2 = recs[e + 2], r3 = recs[e + 3];
    float h0 = bf2f(Hb[(size_t)r0.x * HD + lane]);
    float h1 = bf2f(Hb[(size_t)r1.x * HD + lane]);
    float h2 = bf2f(Hb[(size_t)r2.x * HD + lane]);
    float h3 = bf2f(Hb[(size_t)r3.x * HD + lane]);
    acc = fmaf(h0, __int_as_float(r0.y), acc);
    acc = fmaf(h1, __int_as_float(r1.y), acc);
    acc = fmaf(h2, __int_as_float(r2.y), acc);
    acc = fmaf(h3, __int_as_float(r3.y), acc);
  }
  for (; e < end; ++e) {
    int2 r = recs[e];
    acc = fmaf(bf2f(Hb[(size_t)r.x * HD + lane]), __int_as_float(r.y), acc);
  }
  acc += bias[lane];
  if (relu) acc = fmaxf(acc, 0.f);
  out[(size_t)node * HD + lane] = acc;
}

// ---------------- zscore ----------------

__global__ void k_colstats(const float* __restrict__ H, float* __restrict__ stats, int N) {
  __shared__ float ss[256], sq[256];
  int t = threadIdx.x;
  int col = t & 63, grp = t >> 6;
  float s = 0.f, q = 0.f;
  for (int row = blockIdx.x * 4 + grp; row < N; row += gridDim.x * 4) {
    float v = H[(size_t)row * HD + col];
    s += v;
    q += v * v;
  }
  ss[t] = s;
  sq[t] = q;
  __syncthreads();
  if (t < 64) {
    s = ss[t] + ss[t + 64] + ss[t + 128] + ss[t + 192];
    q = sq[t] + sq[t + 64] + sq[t + 128] + sq[t + 192];
    atomicAdd(&stats[t], s);
    atomicAdd(&stats[64 + t], q);
  }
}

__global__ void k_normalize(float* __restrict__ H, const float* __restrict__ stats, int N) {
  int i = blockIdx.x * blockDim.x + threadIdx.x;
  int total = N * HD;
  if (i >= total) return;
  int col = i & 63;
  float sum = stats[col], sumsq = stats[64 + col];
  float mean = sum / (float)N;
  float var = (sumsq - sum * sum / (float)N) / (float)(N - 1);
  float r = rsqrtf(var);
  H[i] = (H[i] - mean) * r;
}

// ---------------- launch ----------------

extern "C" void kernel_launch(void* const* d_in, const int* in_sizes, int n_in,
                              void* d_out, int out_size, void* d_ws, size_t ws_size,
                              hipStream_t stream) {
  const int IN_DIM = 256;
  const float* X[2] = {(const float*)d_in[0], (const float*)d_in[2]};
  const int* EI[2] = {(const int*)d_in[1], (const int*)d_in[3]};
  const float* W1 = (const float*)d_in[4];
  const float* b1 = (const float*)d_in[5];
  const float* W2 = (const float*)d_in[6];
  const float* b2 = (const float*)d_in[7];
  const int N = in_sizes[0] / IN_DIM;
  const int E = in_sizes[1] / 2;

  // workspace carve-up (~55 MB)
  char* ws = (char*)d_ws;
  size_t off = 0;
  auto carve = [&](size_t bytes) -> char* {
    char* p = ws + off;
    off += (bytes + 255) & ~(size_t)255;
    return p;
  };
  unsigned short* Hb = (unsigned short*)carve((size_t)N * HD * 2);  // bf16 gemm out
  float* bufB = (float*)carve((size_t)N * HD * 4);                  // f32 agg out
  int2* recs = (int2*)carve((size_t)E * 8);
  // contiguous zero region: deg[N] | cursor[N] | stats[128]
  char* zero_base = carve(((size_t)2 * N + 128) * 4);
  int* deg = (int*)zero_base;
  int* cursor = deg + N;
  float* stats = (float*)(cursor + N);
  int* row_start = (int*)carve((size_t)(N + 1) * 4);
  float* dinv = (float*)carve((size_t)N * 4);
  int* partials = (int*)carve(256 * 4);
  (void)ws_size; (void)n_in; (void)out_size;

  const int T = 256;
  const int gE = (E + T - 1) / T;
  const int gN = (N + T - 1) / T;
  const int nchunk = (N + 1023) / 1024;
  const int gWave4 = (N + 3) / 4;    // one wave per node, 4 waves/block
  const int gGemm = (N + 63) / 64;   // 64 rows per block
  const int gElem = (N * HD + T - 1) / T;

  for (int g = 0; g < 2; ++g) {
    const float* x = X[g];
    const int* src = EI[g];
    const int* dst = EI[g] + E;
    float* OUT = (float*)d_out + (size_t)g * N * HD;

    hipMemsetAsync(zero_base, 0, ((size_t)2 * N + 128) * 4, stream);
    k_deg<<<gE, T, 0, stream>>>(dst, deg, E);
    k_scan1<<<nchunk, T, 0, stream>>>(deg, row_start, partials, dinv, N);
    k_scan2<<<1, T, 0, stream>>>(partials, nchunk);
    k_scan3<<<gN, T, 0, stream>>>(row_start, partials, N, E);
    k_fill<<<gE, T, 0, stream>>>(src, dst, row_start, cursor, dinv, recs, E);

    // layer 1: h = relu(agg(x @ W1) + b1)
    k_gemm_mfma<256, 128><<<gGemm, T, 0, stream>>>(x, W1, Hb, N);
    k_agg<<<gWave4, T, 0, stream>>>(Hb, recs, row_start, dinv, b1, bufB, N, 1);
    // layer 2: h = agg(h1 @ W2) + b2 -> straight into d_out segment
    k_gemm_mfma<64, 64><<<gGemm, T, 0, stream>>>(bufB, W2, Hb, N);
    k_agg<<<gWave4, T, 0, stream>>>(Hb, recs, row_start, dinv, b2, OUT, N, 0);

    // zscore in place on OUT
    k_colstats<<<512, T, 0, stream>>>(OUT, stats, N);
    k_normalize<<<gElem, T, 0, stream>>>(OUT, stats, N);
  }
}